// Round 2
// 554.199 us; speedup vs baseline: 1.0395x; 1.0395x over previous
//
#include <hip/hip_runtime.h>

// ---------------------------------------------------------------------------
// SparseLoRAMoE: out = (gate ⊙ (x @ A_flat^T)) @ Bflat * 0.5
//   N=16384 tokens, D=4096, E=8 experts, R=16, C=E*R=128, O=4096, TOP_K=2
// Round 2: resubmit of Round-1 fused pipeline (Round-1 bench was an infra
// flake: "container failed twice", no pytest/profile output).
//   - router fused into gemm1 (fp32 logits from the same x registers)
//   - gates + combine fused into gemm1 epilogue -> Mg bf16 written directly
//   - 3 kernels total: prep, g1f, g2
// ---------------------------------------------------------------------------

#define NTOK   16384
#define DDIM   4096
#define NEXP   8
#define CDIM   128     // E*R
#define ODIM   4096

typedef float  f32x4  __attribute__((ext_vector_type(4)));
typedef __bf16 bf16x8 __attribute__((ext_vector_type(8)));
typedef unsigned short ushort8 __attribute__((ext_vector_type(8)));

__device__ __forceinline__ unsigned short f2bf(float f) {
    union { float f; unsigned u; } v; v.f = f;
    unsigned r = v.u + 0x7FFFu + ((v.u >> 16) & 1u);   // RNE
    return (unsigned short)(r >> 16);
}

// ---------------------------------------------------------------------------
// prep: A [128,4096] fp32 -> bf16 (same layout); Bm [8,4096,16] fp32 ->
//       Bt [o=4096][c=128] bf16 (o-major, c contiguous)
// grid 4096 x 256
// ---------------------------------------------------------------------------
__global__ void prep_kernel(const float* __restrict__ A,
                            const float* __restrict__ Bm,
                            unsigned short* __restrict__ A_bf,
                            unsigned short* __restrict__ Bt) {
    int i = blockIdx.x * 256 + threadIdx.x;
    if (i < CDIM * DDIM) {
        A_bf[i] = f2bf(A[i]);
    } else {
        int j = i - CDIM * DDIM;           // j = o*128 + c
        int o = j >> 7, c = j & 127;
        int e = c >> 4, r = c & 15;
        Bt[j] = f2bf(Bm[((size_t)e * ODIM + o) * 16 + r]);
    }
}

// ---------------------------------------------------------------------------
// g1f: fused router + gemm1 + gates + combine.
//   Mg[n][c] = bf16( (x bf16 @ A^T)[n][c] * gate[n][c>>4] * 0.5 )
// BM=32, BK=32, full K=4096 (128 iters). grid 512 (2 blocks/CU), 256 thr.
// Router logits accumulated in fp32 from the SAME x registers used for
// bf16 conversion (exact selection vs reference; no second x pass).
// Waves: (wv&1) = row group of 16, (wv>>1) = col frags {0-3} / {4-7}.
// ---------------------------------------------------------------------------
__global__ __launch_bounds__(256, 2) void g1f_kernel(const float* __restrict__ x,
                                                     const unsigned short* __restrict__ A_bf,
                                                     const float* __restrict__ rw,
                                                     const float* __restrict__ rbias,
                                                     unsigned short* __restrict__ Mg) {
    __shared__ alignas(16) unsigned short xt[32 * 40];    // [row][32+8 pad]
    __shared__ alignas(16) unsigned short at[128 * 40];
    __shared__ float gateLds[32][NEXP];

    int tid = threadIdx.x;
    int wv = tid >> 6, lane = tid & 63;
    int row0 = blockIdx.x * 32;

    // x staging: thread -> row (tid>>3), 4 floats at k = (tid&7)*4
    int sr = tid >> 3, sq = tid & 7;
    const float* xsrc = x + (size_t)(row0 + sr) * DDIM + sq * 4;
    // A staging: thread -> row (tid>>1), 16 bf16 at (tid&1)*16
    int ac = tid >> 1, ah = tid & 1;
    const unsigned short* asrc = A_bf + (size_t)ac * DDIM + ah * 16;
    // router weights: same k positions as this thread's x chunk
    const float* rsrc = rw + sq * 4;

    int xoff = sr * 40 + sq * 4;
    int aoff = ac * 40 + ah * 16;

    f32x4 acc[4];
    #pragma unroll
    for (int f = 0; f < 4; f++) acc[f] = (f32x4){0.f, 0.f, 0.f, 0.f};
    float racc[NEXP];
    #pragma unroll
    for (int e = 0; e < NEXP; e++) racc[e] = 0.f;

    // prefetch tile 0
    float4 px  = *(const float4*)(xsrc);
    uint4  pa0 = *(const uint4*)(asrc);
    uint4  pa1 = *(const uint4*)(asrc + 8);
    float4 pr[NEXP];
    #pragma unroll
    for (int e = 0; e < NEXP; e++)
        pr[e] = *(const float4*)(rsrc + (size_t)e * DDIM);

    int am = ((wv & 1) * 16 + (lane & 15)) * 40 + (lane >> 4) * 8;
    int bq = (lane & 15) * 40 + (lane >> 4) * 8;
    int fbase = (wv >> 1) * 4;

    for (int it = 0; it < 128; it++) {
        ushort4 xw;
        xw.x = f2bf(px.x); xw.y = f2bf(px.y);
        xw.z = f2bf(px.z); xw.w = f2bf(px.w);
        // router accumulation in fp32 on the register copy of x
        #pragma unroll
        for (int e = 0; e < NEXP; e++)
            racc[e] += px.x * pr[e].x + px.y * pr[e].y +
                       px.z * pr[e].z + px.w * pr[e].w;
        if (it) __syncthreads();           // previous tile's readers done
        *(ushort4*)(&xt[xoff]) = xw;
        *(uint4*)(&at[aoff])     = pa0;
        *(uint4*)(&at[aoff + 8]) = pa1;
        if (it + 1 < 128) {                // issue next-tile loads, overlap MFMA
            xsrc += 32;  asrc += 32;  rsrc += 32;
            px  = *(const float4*)(xsrc);
            pa0 = *(const uint4*)(asrc);
            pa1 = *(const uint4*)(asrc + 8);
            #pragma unroll
            for (int e = 0; e < NEXP; e++)
                pr[e] = *(const float4*)(rsrc + (size_t)e * DDIM);
        }
        __syncthreads();
        bf16x8 a = *(bf16x8*)(&xt[am]);
        #pragma unroll
        for (int f = 0; f < 4; f++) {
            bf16x8 b = *(bf16x8*)(&at[(fbase + f) * 16 * 40 + bq]);
            acc[f] = __builtin_amdgcn_mfma_f32_16x16x32_bf16(a, b, acc[f], 0, 0, 0);
        }
    }

    // --- router epilogue: reduce the 8 quad-lanes of each row ---------------
    #pragma unroll
    for (int e = 0; e < NEXP; e++) {
        float v = racc[e];
        v += __shfl_xor(v, 1, 64);
        v += __shfl_xor(v, 2, 64);
        v += __shfl_xor(v, 4, 64);
        racc[e] = v + rbias[e];
    }
    // top-2 softmax gates (uniform within each 8-lane row group)
    int a1 = 0; float m1 = racc[0];
    #pragma unroll
    for (int e = 1; e < NEXP; e++) if (racc[e] > m1) { m1 = racc[e]; a1 = e; }
    int a2 = -1; float m2 = -3.0e38f;
    #pragma unroll
    for (int e = 0; e < NEXP; e++) if (e != a1 && racc[e] > m2) { m2 = racc[e]; a2 = e; }
    float g1v = 1.f / (1.f + expf(m2 - m1));
    float g2v = 1.f - g1v;
    if ((tid & 7) == 0) {
        #pragma unroll
        for (int e = 0; e < NEXP; e++)
            gateLds[sr][e] = (e == a1) ? g1v * 0.5f : ((e == a2) ? g2v * 0.5f : 0.f);
    }
    __syncthreads();

    // --- gated bf16 write of Mg --------------------------------------------
    int rowb = (wv & 1) * 16 + (lane >> 4) * 4;
    int cl = lane & 15;
    #pragma unroll
    for (int f = 0; f < 4; f++) {
        int e = fbase + f;
        #pragma unroll
        for (int r = 0; r < 4; r++) {
            float g = gateLds[rowb + r][e];
            Mg[(size_t)(row0 + rowb + r) * CDIM + e * 16 + cl] = f2bf(acc[f][r] * g);
        }
    }
}

// ---------------------------------------------------------------------------
// gemm2: out[n][o] = sum_c Mg[n][c] * Bt[o][c]   (K=128, single shot)
// BM=64, BN=128 -> grid 8192 (256 row-blocks x 32 col-blocks), 256 threads.
// ---------------------------------------------------------------------------
__global__ __launch_bounds__(256, 2) void g2_kernel(const unsigned short* __restrict__ Mg,
                                                    const unsigned short* __restrict__ Bt,
                                                    float* __restrict__ out) {
    __shared__ alignas(16) unsigned short mt[64 * 136];    // [row][128+8]
    __shared__ alignas(16) unsigned short bt[128 * 136];

    int tid = threadIdx.x, wv = tid >> 6, lane = tid & 63;
    int cb = blockIdx.x & 31, rb = blockIdx.x >> 5;
    int row0 = rb * 64, col0 = cb * 128;

    {   // stage M tile: 64 x 128 bf16 = 16 KB, 64 B/thread
        int r = tid >> 2, q = tid & 3;
        const uint4* src = (const uint4*)(Mg + (size_t)(row0 + r) * CDIM + q * 32);
        uint4 v0 = src[0], v1 = src[1], v2 = src[2], v3 = src[3];
        uint4* dst = (uint4*)(&mt[r * 136 + q * 32]);
        dst[0] = v0; dst[1] = v1; dst[2] = v2; dst[3] = v3;
    }
    {   // stage B tile: 128 x 128 bf16 = 32 KB, 128 B/thread
        int o = tid >> 1, h = tid & 1;
        const uint4* src = (const uint4*)(Bt + (size_t)(col0 + o) * CDIM + h * 64);
        uint4 v0 = src[0], v1 = src[1], v2 = src[2], v3 = src[3];
        uint4 v4 = src[4], v5 = src[5], v6 = src[6], v7 = src[7];
        uint4* dst = (uint4*)(&bt[o * 136 + h * 64]);
        dst[0] = v0; dst[1] = v1; dst[2] = v2; dst[3] = v3;
        dst[4] = v4; dst[5] = v5; dst[6] = v6; dst[7] = v7;
    }
    __syncthreads();

    f32x4 acc[8];
    #pragma unroll
    for (int f = 0; f < 8; f++) acc[f] = (f32x4){0.f, 0.f, 0.f, 0.f};

    int mrow = (wv * 16 + (lane & 15)) * 136;
    int kq = (lane >> 4) * 8;
    #pragma unroll
    for (int kk = 0; kk < 4; kk++) {
        bf16x8 a = *(bf16x8*)(&mt[mrow + kk * 32 + kq]);
        #pragma unroll
        for (int f = 0; f < 8; f++) {
            bf16x8 b = *(bf16x8*)(&bt[(f * 16 + (lane & 15)) * 136 + kk * 32 + kq]);
            acc[f] = __builtin_amdgcn_mfma_f32_16x16x32_bf16(a, b, acc[f], 0, 0, 0);
        }
    }

    int rbase = row0 + wv * 16 + (lane >> 4) * 4;
    int cl = lane & 15;
    #pragma unroll
    for (int f = 0; f < 8; f++)
        #pragma unroll
        for (int r = 0; r < 4; r++)
            out[(size_t)(rbase + r) * ODIM + col0 + f * 16 + cl] = acc[f][r];
}

// ---------------------------------------------------------------------------
extern "C" void kernel_launch(void* const* d_in, const int* in_sizes, int n_in,
                              void* d_out, int out_size, void* d_ws, size_t ws_size,
                              hipStream_t stream) {
    const float* x    = (const float*)d_in[0];
    const float* rw   = (const float*)d_in[1];
    const float* rbia = (const float*)d_in[2];
    const float* A    = (const float*)d_in[3];
    const float* Bm   = (const float*)d_in[4];
    float* out = (float*)d_out;

    char* ws = (char*)d_ws;
    unsigned short* A_bf = (unsigned short*)(ws);                 // 1 MB
    unsigned short* Bt   = (unsigned short*)(ws + (1u << 20));    // 1 MB
    unsigned short* Mg   = (unsigned short*)(ws + (2u << 20));    // 4 MB

    prep_kernel<<<4096, 256, 0, stream>>>(A, Bm, A_bf, Bt);
    g1f_kernel <<< 512, 256, 0, stream>>>(x, A_bf, rw, rbia, Mg);
    g2_kernel  <<<8192, 256, 0, stream>>>(Mg, Bt, out);
}